// Round 1
// 915.338 us; speedup vs baseline: 4.2844x; 4.2844x over previous
//
#include <hip/hip_runtime.h>
#include <hip/hip_bf16.h>
#include <hip/hip_fp16.h>

// GRU scan, B=128 T=1024 D=256 H=256. ALL I/O IS FLOAT32 (per reference).
// Kernel 1 (UNCHANGED, verified): xp = obs @ Wi + bi -> d_ws as f16 [131072, 768]
// Kernel 2 (REWRITE): segment-parallel MFMA scan.
//   Key insight: done ~ Bernoulli(0.5) resets h<-0 BEFORE the step, so the
//   timeline splits into independent segments. Chunk T into 32 chunks of 32
//   steps; block (grp,chunk) activates batch b at the first done>=t0 (true h
//   is exactly 0 there) and releases it at the first done >= tend (where the
//   next chunk's block activates). Exactly-once writes, no inter-block comms.
//   Each block: 16 batch rows x 768 cols per step via mfma_f32_16x16x32_f16,
//   weights resident in 384 regs/lane (unified VGPR+AGPR file, 1 wave/SIMD),
//   h in 16KB double-buffered XOR-swizzled LDS, 1 barrier/step.
// Fragment conventions copied from the verified xproj_gemm:
//   A: row=lane&15, k=(lane>>4)*8+j ; B: col=lane&15, k=(lane>>4)*8+j
//   C: col=lane&15, row=(lane>>4)*4+reg   (row=batch, col=n-position)
// R2 lesson kept: weight arrays must be FULLY unrolled -> constant indices
// -> SROA -> registers (never scratch).

#define B_ 128
#define T_ 1024
#define D_ 256
#define H_ 256
#define CHUNKS_ 32
#define CHUNK_T_ (T_ / CHUNKS_)   // 32

typedef _Float16 half2v __attribute__((ext_vector_type(2)));
typedef _Float16 half8v __attribute__((ext_vector_type(8)));
typedef float f32x4 __attribute__((ext_vector_type(4)));

// ---------------- Kernel 1: xp = obs @ Wi + bi (UNCHANGED) ----------------
__global__ __launch_bounds__(256, 2) void xproj_gemm(
    const float* __restrict__ A,    // obs [131072, 256] fp32
    const float* __restrict__ W,    // Wi  [256, 768] fp32
    const float* __restrict__ bias, // bi  [768] fp32
    _Float16* __restrict__ C)       // xp  [131072, 768] f16
{
  constexpr int LDS_K = 40;  // 32 + 8 pad
  __shared__ __align__(16) _Float16 As[128 * LDS_K];   // [m][k]
  __shared__ __align__(16) _Float16 Bs[128 * LDS_K];   // [n][k] (transposed)
  const int m0 = blockIdx.x * 128;
  const int n0 = blockIdx.y * 128;
  const int tid = threadIdx.x;
  const int lane = tid & 63;
  const int wv = tid >> 6;
  const int wm = (wv >> 1) * 64;   // wave's 64x64 quadrant
  const int wn = (wv & 1) * 64;
  const int q = lane >> 4;
  const int lm = lane & 15;

  f32x4 acc[4][4];
#pragma unroll
  for (int i = 0; i < 4; ++i)
#pragma unroll
    for (int j = 0; j < 4; ++j)
      acc[i][j] = (f32x4){0.f, 0.f, 0.f, 0.f};

  const int ar = tid >> 1, ac = (tid & 1) * 16;
  const int bk = tid >> 3, bj = (tid & 7) * 16;

  for (int k0 = 0; k0 < 256; k0 += 32) {
    const float* ap = A + (size_t)(m0 + ar) * 256 + k0 + ac;
    float4 a0 = *(const float4*)(ap + 0);
    float4 a1 = *(const float4*)(ap + 4);
    float4 a2 = *(const float4*)(ap + 8);
    float4 a3 = *(const float4*)(ap + 12);
    const float* bp = W + (size_t)(k0 + bk) * 768 + n0 + bj;
    float4 b0 = *(const float4*)(bp + 0);
    float4 b1 = *(const float4*)(bp + 4);
    float4 b2 = *(const float4*)(bp + 8);
    float4 b3 = *(const float4*)(bp + 12);

    _Float16 av[16];
    av[0] = (_Float16)a0.x; av[1] = (_Float16)a0.y; av[2] = (_Float16)a0.z; av[3] = (_Float16)a0.w;
    av[4] = (_Float16)a1.x; av[5] = (_Float16)a1.y; av[6] = (_Float16)a1.z; av[7] = (_Float16)a1.w;
    av[8] = (_Float16)a2.x; av[9] = (_Float16)a2.y; av[10] = (_Float16)a2.z; av[11] = (_Float16)a2.w;
    av[12] = (_Float16)a3.x; av[13] = (_Float16)a3.y; av[14] = (_Float16)a3.z; av[15] = (_Float16)a3.w;
    *(int4*)&As[ar * LDS_K + ac] = *(int4*)&av[0];
    *(int4*)&As[ar * LDS_K + ac + 8] = *(int4*)&av[8];

    _Float16 bvv[16];
    bvv[0] = (_Float16)b0.x; bvv[1] = (_Float16)b0.y; bvv[2] = (_Float16)b0.z; bvv[3] = (_Float16)b0.w;
    bvv[4] = (_Float16)b1.x; bvv[5] = (_Float16)b1.y; bvv[6] = (_Float16)b1.z; bvv[7] = (_Float16)b1.w;
    bvv[8] = (_Float16)b2.x; bvv[9] = (_Float16)b2.y; bvv[10] = (_Float16)b2.z; bvv[11] = (_Float16)b2.w;
    bvv[12] = (_Float16)b3.x; bvv[13] = (_Float16)b3.y; bvv[14] = (_Float16)b3.z; bvv[15] = (_Float16)b3.w;
#pragma unroll
    for (int i = 0; i < 16; ++i) Bs[(bj + i) * LDS_K + bk] = bvv[i];
    __syncthreads();

    half8v af[4], bfr[4];
#pragma unroll
    for (int i = 0; i < 4; ++i)
      af[i] = *(const half8v*)&As[(wm + i * 16 + lm) * LDS_K + q * 8];
#pragma unroll
    for (int j = 0; j < 4; ++j)
      bfr[j] = *(const half8v*)&Bs[(wn + j * 16 + lm) * LDS_K + q * 8];
#pragma unroll
    for (int i = 0; i < 4; ++i)
#pragma unroll
      for (int j = 0; j < 4; ++j)
        acc[i][j] = __builtin_amdgcn_mfma_f32_16x16x32_f16(af[i], bfr[j], acc[i][j], 0, 0, 0);
    __syncthreads();
  }

#pragma unroll
  for (int j = 0; j < 4; ++j) {
    const int n = n0 + wn + j * 16 + lm;
    const float bv = bias[n];
#pragma unroll
    for (int i = 0; i < 4; ++i) {
#pragma unroll
      for (int r = 0; r < 4; ++r) {
        const int m = m0 + wm + i * 16 + q * 4 + r;
        C[(size_t)m * 768 + n] = (_Float16)(acc[i][j][r] + bv);
      }
    }
  }
}

// ---------------- Kernel 2: segment-parallel MFMA GRU scan ----------------
// Grid: 256 blocks = 8 batch-groups x 32 time-chunks. 256 threads (4 waves).
// Wave w owns n-cols [w*64, w*64+64) of each role (r|z|n) = 12 N-tiles.

// XOR swizzle (G4): spreads the 512B-row-stride LDS tile across banks.
// Applied identically on ds_write_b16 / ds_read_b128 / ds_read_u16.
__device__ __forceinline__ int swzb(int row, int colbyte) {
  return row * 512 + (colbyte ^ ((row & 7) << 4));
}

__global__ __launch_bounds__(256, 1) void gru_scan_mfma(
    const _Float16* __restrict__ xp,  // [B*T, 768] f16
    const int* __restrict__ done,     // [B, T] int32
    const float* __restrict__ h0,     // [B, H] fp32
    const float* __restrict__ Wh_rz,  // [H, 2H] fp32
    const float* __restrict__ Wh_n,   // [H, H] fp32
    const float* __restrict__ bh_n,   // [H] fp32
    float* __restrict__ out_final,    // [B, H] fp32
    float* __restrict__ out_ys)       // [B, T, H] fp32
{
  const int bx = blockIdx.x;
  const int grp = bx & 7;            // batch group (16 batches)
  const int chunk = bx >> 3;         // time chunk
  const int t0 = chunk * CHUNK_T_;
  const int tend = t0 + CHUNK_T_;
  const int tid = threadIdx.x;
  const int w = tid >> 6;            // wave 0..3
  const int l = tid & 63;
  const int lm = l & 15;
  const int q = l >> 4;
  const int colb = w * 64 + lm;      // this lane's base column (cg adds *16)

  __shared__ __align__(16) _Float16 h_lds[2][16 * 256];  // 16KB, swizzled

  // ---- B fragments resident in registers: bf[role][colgroup][kstep] ----
  // elem j of frag = W[k = kc*32 + q*8 + j][n = ro*256 + colb + cg*16]
  // FULL unroll mandatory (R2): constant indices => SROA => registers.
  half8v bf[3][4][8];
#pragma unroll
  for (int ro = 0; ro < 3; ++ro)
#pragma unroll
    for (int cg = 0; cg < 4; ++cg)
#pragma unroll
      for (int kc = 0; kc < 8; ++kc) {
        half8v v;
#pragma unroll
        for (int j = 0; j < 8; ++j) {
          const int k = kc * 32 + q * 8 + j;
          const int c = colb + cg * 16;
          const float wv = (ro < 2) ? Wh_rz[(size_t)k * 512 + ro * 256 + c]
                                    : Wh_n[(size_t)k * 256 + c];
          v[j] = (_Float16)wv;
        }
        bf[ro][cg][kc] = v;
      }

  float bhn[4];
#pragma unroll
  for (int cg = 0; cg < 4; ++cg) bhn[cg] = bh_n[colb + cg * 16];

  // ---- per-batch-row pointers (4 C-rows per lane: batch = grp*16+q*4+r) ----
  const _Float16* xrow[4];
  float* yrow[4];
  const int* drow[4];
  int dcur[4];
#pragma unroll
  for (int r = 0; r < 4; ++r) {
    const int b = grp * 16 + q * 4 + r;
    xrow[r] = xp + ((size_t)b * T_ + t0) * 768;
    yrow[r] = out_ys + ((size_t)b * T_ + t0) * H_;
    drow[r] = done + (size_t)b * T_ + t0;
    dcur[r] = drow[r][0];
  }

  // ---- init h tile: chunk 0 starts from h0 (masked by done[b,0]); others 0.
  // Pre-activation h is garbage-but-bounded (0-init); writes are suppressed
  // until the first done (where true h == 0 exactly).
  char* hR = (char*)&h_lds[0][0];
  char* hW = (char*)&h_lds[1][0];
#pragma unroll
  for (int cg = 0; cg < 4; ++cg)
#pragma unroll
    for (int r = 0; r < 4; ++r) {
      const int row = q * 4 + r;
      const int c = colb + cg * 16;
      float v = 0.f;
      if (chunk == 0) {
        const int b = grp * 16 + row;
        v = done[(size_t)b * T_] ? 0.f : h0[(size_t)b * H_ + c];
      }
      *(_Float16*)(hR + swzb(row, c * 2)) = (_Float16)v;
    }
  __syncthreads();

  unsigned act = (chunk == 0) ? 0xFu : 0u;  // batch live for output writes
  unsigned endm = 0u;                        // batch handed to next chunk

  for (int t = t0;;) {
    // flag update with done[b,t] (reset happens BEFORE the step in the ref)
#pragma unroll
    for (int r = 0; r < 4; ++r)
      if (dcur[r]) {
        if (t >= tend) endm |= (1u << r);
        else           act  |= (1u << r);
      }
    if (t >= T_) break;
    if (__all(endm == 0xFu)) break;   // all 16 batches handed off

    // done[b,t+1] -> masks NEXT step's h entry (written into hW below).
    // t+1==T_ => no mask (final h is un-masked in the reference).
    int dn[4];
    const int tn = (t + 1 < T_) ? 1 : 0;
#pragma unroll
    for (int r = 0; r < 4; ++r) {
      const int v = drow[r][tn];
      dn[r] = (t + 1 < T_) ? v : 0;
    }

    // A fragments: h rows (batch=lm), k = kc*32 + q*8 + j
    half8v a[8];
#pragma unroll
    for (int kc = 0; kc < 8; ++kc)
      a[kc] = *(const half8v*)(hR + swzb(lm, kc * 64 + q * 16));

    // two N-halves to cap accumulator liveness at 24 regs
#pragma unroll
    for (int hf = 0; hf < 2; ++hf) {
      f32x4 acc[3][2];
#pragma unroll
      for (int ro = 0; ro < 3; ++ro)
#pragma unroll
        for (int c2 = 0; c2 < 2; ++c2)
          acc[ro][c2] = (f32x4){0.f, 0.f, 0.f, 0.f};

#pragma unroll
      for (int kc = 0; kc < 8; ++kc)
#pragma unroll
        for (int ro = 0; ro < 3; ++ro)
#pragma unroll
          for (int c2 = 0; c2 < 2; ++c2)
            acc[ro][c2] = __builtin_amdgcn_mfma_f32_16x16x32_f16(
                a[kc], bf[ro][hf * 2 + c2][kc], acc[ro][c2], 0, 0, 0);

      // epilogue for this half: 8 (batch,col) cells per lane
#pragma unroll
      for (int c2 = 0; c2 < 2; ++c2) {
        const int cg = hf * 2 + c2;
        const int col = colb + cg * 16;
#pragma unroll
        for (int r = 0; r < 4; ++r) {
          const int row = q * 4 + r;
          const float xr = (float)xrow[r][col];
          const float xz = (float)xrow[r][col + 256];
          const float xn = (float)xrow[r][col + 512];
          const float hm = (float)*(const _Float16*)(hR + swzb(row, col * 2));
          const float sr = xr + acc[0][c2][r];
          const float sz = xz + acc[1][c2][r];
          const float rr = 1.f / (1.f + __expf(-sr));
          const float zz = 1.f / (1.f + __expf(-sz));
          const float npre = xn + rr * (acc[2][c2][r] + bhn[cg]);
          const float e = __expf(-2.f * fabsf(npre));   // saturating tanh
          const float tv = (1.f - e) / (1.f + e);
          const float nn = npre < 0.f ? -tv : tv;
          const float hnew = (1.f - zz) * nn + zz * hm;
          // next-step h, masked by done[t+1] (A-reads then need no mask)
          *(_Float16*)(hW + swzb(row, col * 2)) =
              (_Float16)(dn[r] ? 0.f : hnew);
          if (((act >> r) & 1u) && !((endm >> r) & 1u)) {
            yrow[r][col] = hnew;
            if (t == T_ - 1)
              out_final[(size_t)(grp * 16 + row) * H_ + col] = hnew;
          }
        }
      }
    }

#pragma unroll
    for (int r = 0; r < 4; ++r) {
      xrow[r] += 768;
      yrow[r] += H_;
      drow[r] += 1;
      dcur[r] = dn[r];
    }
    { char* tmp = hR; hR = hW; hW = tmp; }
    ++t;
    __syncthreads();
  }
}

extern "C" void kernel_launch(void* const* d_in, const int* in_sizes, int n_in,
                              void* d_out, int out_size, void* d_ws, size_t ws_size,
                              hipStream_t stream) {
  const float* obs   = (const float*)d_in[0];
  const int*   done  = (const int*)d_in[1];
  const float* h0    = (const float*)d_in[2];
  const float* Wi    = (const float*)d_in[3];
  const float* bi    = (const float*)d_in[4];
  const float* Wh_rz = (const float*)d_in[5];
  const float* Wh_n  = (const float*)d_in[6];
  const float* bh_n  = (const float*)d_in[7];
  float* out = (float*)d_out;                 // [final_h (B*H) | ys (B*T*H)]
  _Float16* xp = (_Float16*)d_ws;             // [131072, 768] f16 (201 MB)

  xproj_gemm<<<dim3(1024, 6), 256, 0, stream>>>(obs, Wi, bi, xp);
  gru_scan_mfma<<<dim3(256), 256, 0, stream>>>(xp, done, h0, Wh_rz, Wh_n, bh_n,
                                               out, out + B_ * H_);
}

// Round 2
// 869.434 us; speedup vs baseline: 4.5106x; 1.0528x over previous
//
#include <hip/hip_runtime.h>
#include <hip/hip_bf16.h>
#include <hip/hip_fp16.h>

// GRU scan, B=128 T=1024 D=256 H=256. ALL I/O IS FLOAT32 (per reference).
// Kernel 1 (UNCHANGED, verified): xp = obs @ Wi + bi -> d_ws as f16 [131072, 768]
// Kernel 2: segment-parallel MFMA scan (verified R1 structure) + R2 fixes:
//   R2a: xp staged through LDS via double-buffered global_load_lds prefetch
//        (issued for t+1 at top of step t; the compiler's vmcnt(0) drain at
//        __syncthreads is the completion sync). Source chunk index is
//        pre-swizzled (chunk ^= row&7) so the strided epilogue reads are
//        conflict-free; LDS dest stays linear (global_load_lds requirement).
//   R2b: xr/xz folded into MFMA accumulator init (bh_n into the n-acc);
//        only xn remains as an epilogue LDS read.
//   R2c: done[t+1] loads hoisted to step top (consumed ~2K cycles later).
//   R2d: sched_barrier(0) fence per 64 weight loads in the prologue so LLVM
//        cannot hoist all 768 strided loads and spill bf[] to scratch
//        (R1 counters: WRITE_SIZE 226MB vs 128MB expected = 98MB spill
//        = exactly bf[] size across all threads).
// R2 lesson kept: weight/index arrays FULLY unrolled -> constant indices
// -> SROA -> registers.

#define B_ 128
#define T_ 1024
#define D_ 256
#define H_ 256
#define CHUNKS_ 32
#define CHUNK_T_ (T_ / CHUNKS_)   // 32

typedef _Float16 half2v __attribute__((ext_vector_type(2)));
typedef _Float16 half8v __attribute__((ext_vector_type(8)));
typedef float f32x4 __attribute__((ext_vector_type(4)));

// ---------------- Kernel 1: xp = obs @ Wi + bi (UNCHANGED) ----------------
__global__ __launch_bounds__(256, 2) void xproj_gemm(
    const float* __restrict__ A,    // obs [131072, 256] fp32
    const float* __restrict__ W,    // Wi  [256, 768] fp32
    const float* __restrict__ bias, // bi  [768] fp32
    _Float16* __restrict__ C)       // xp  [131072, 768] f16
{
  constexpr int LDS_K = 40;  // 32 + 8 pad
  __shared__ __align__(16) _Float16 As[128 * LDS_K];   // [m][k]
  __shared__ __align__(16) _Float16 Bs[128 * LDS_K];   // [n][k] (transposed)
  const int m0 = blockIdx.x * 128;
  const int n0 = blockIdx.y * 128;
  const int tid = threadIdx.x;
  const int lane = tid & 63;
  const int wv = tid >> 6;
  const int wm = (wv >> 1) * 64;   // wave's 64x64 quadrant
  const int wn = (wv & 1) * 64;
  const int q = lane >> 4;
  const int lm = lane & 15;

  f32x4 acc[4][4];
#pragma unroll
  for (int i = 0; i < 4; ++i)
#pragma unroll
    for (int j = 0; j < 4; ++j)
      acc[i][j] = (f32x4){0.f, 0.f, 0.f, 0.f};

  const int ar = tid >> 1, ac = (tid & 1) * 16;
  const int bk = tid >> 3, bj = (tid & 7) * 16;

  for (int k0 = 0; k0 < 256; k0 += 32) {
    const float* ap = A + (size_t)(m0 + ar) * 256 + k0 + ac;
    float4 a0 = *(const float4*)(ap + 0);
    float4 a1 = *(const float4*)(ap + 4);
    float4 a2 = *(const float4*)(ap + 8);
    float4 a3 = *(const float4*)(ap + 12);
    const float* bp = W + (size_t)(k0 + bk) * 768 + n0 + bj;
    float4 b0 = *(const float4*)(bp + 0);
    float4 b1 = *(const float4*)(bp + 4);
    float4 b2 = *(const float4*)(bp + 8);
    float4 b3 = *(const float4*)(bp + 12);

    _Float16 av[16];
    av[0] = (_Float16)a0.x; av[1] = (_Float16)a0.y; av[2] = (_Float16)a0.z; av[3] = (_Float16)a0.w;
    av[4] = (_Float16)a1.x; av[5] = (_Float16)a1.y; av[6] = (_Float16)a1.z; av[7] = (_Float16)a1.w;
    av[8] = (_Float16)a2.x; av[9] = (_Float16)a2.y; av[10] = (_Float16)a2.z; av[11] = (_Float16)a2.w;
    av[12] = (_Float16)a3.x; av[13] = (_Float16)a3.y; av[14] = (_Float16)a3.z; av[15] = (_Float16)a3.w;
    *(int4*)&As[ar * LDS_K + ac] = *(int4*)&av[0];
    *(int4*)&As[ar * LDS_K + ac + 8] = *(int4*)&av[8];

    _Float16 bvv[16];
    bvv[0] = (_Float16)b0.x; bvv[1] = (_Float16)b0.y; bvv[2] = (_Float16)b0.z; bvv[3] = (_Float16)b0.w;
    bvv[4] = (_Float16)b1.x; bvv[5] = (_Float16)b1.y; bvv[6] = (_Float16)b1.z; bvv[7] = (_Float16)b1.w;
    bvv[8] = (_Float16)b2.x; bvv[9] = (_Float16)b2.y; bvv[10] = (_Float16)b2.z; bvv[11] = (_Float16)b2.w;
    bvv[12] = (_Float16)b3.x; bvv[13] = (_Float16)b3.y; bvv[14] = (_Float16)b3.z; bvv[15] = (_Float16)b3.w;
#pragma unroll
    for (int i = 0; i < 16; ++i) Bs[(bj + i) * LDS_K + bk] = bvv[i];
    __syncthreads();

    half8v af[4], bfr[4];
#pragma unroll
    for (int i = 0; i < 4; ++i)
      af[i] = *(const half8v*)&As[(wm + i * 16 + lm) * LDS_K + q * 8];
#pragma unroll
    for (int j = 0; j < 4; ++j)
      bfr[j] = *(const half8v*)&Bs[(wn + j * 16 + lm) * LDS_K + q * 8];
#pragma unroll
    for (int i = 0; i < 4; ++i)
#pragma unroll
      for (int j = 0; j < 4; ++j)
        acc[i][j] = __builtin_amdgcn_mfma_f32_16x16x32_f16(af[i], bfr[j], acc[i][j], 0, 0, 0);
    __syncthreads();
  }

#pragma unroll
  for (int j = 0; j < 4; ++j) {
    const int n = n0 + wn + j * 16 + lm;
    const float bv = bias[n];
#pragma unroll
    for (int i = 0; i < 4; ++i) {
#pragma unroll
      for (int r = 0; r < 4; ++r) {
        const int m = m0 + wm + i * 16 + q * 4 + r;
        C[(size_t)m * 768 + n] = (_Float16)(acc[i][j][r] + bv);
      }
    }
  }
}

// ---------------- Kernel 2: segment-parallel MFMA GRU scan ----------------
// Grid: 256 blocks = 8 batch-groups x 32 time-chunks. 256 threads (4 waves).
// Wave w owns n-cols [w*64, w*64+64) of each role (r|z|n) = 12 N-tiles.

// h-tile XOR swizzle (G4): 512B-row-stride tile, spread across banks.
__device__ __forceinline__ int swzb(int row, int colbyte) {
  return row * 512 + (colbyte ^ ((row & 7) << 4));
}

// xp-tile read: row stride 1536B; source-swizzled at stage time with
// chunk ^= row&7, so reads apply the same XOR on byte bits 4..6.
__device__ __forceinline__ int xswz(int row, int colbyte) {
  return row * 1536 + (colbyte ^ ((row & 7) << 4));
}

__device__ __forceinline__ void load16_to_lds(const void* g, void* l) {
  __builtin_amdgcn_global_load_lds(
      (const __attribute__((address_space(1))) unsigned int*)g,
      (__attribute__((address_space(3))) unsigned int*)l, 16, 0, 0);
}

__global__ __launch_bounds__(256, 1) void gru_scan_mfma(
    const _Float16* __restrict__ xp,  // [B*T, 768] f16
    const int* __restrict__ done,     // [B, T] int32
    const float* __restrict__ h0,     // [B, H] fp32
    const float* __restrict__ Wh_rz,  // [H, 2H] fp32
    const float* __restrict__ Wh_n,   // [H, H] fp32
    const float* __restrict__ bh_n,   // [H] fp32
    float* __restrict__ out_final,    // [B, H] fp32
    float* __restrict__ out_ys)       // [B, T, H] fp32
{
  const int bx = blockIdx.x;
  const int grp = bx & 7;            // batch group (16 batches)
  const int chunk = bx >> 3;         // time chunk
  const int t0 = chunk * CHUNK_T_;
  const int tend = t0 + CHUNK_T_;
  const int tid = threadIdx.x;
  const int w = tid >> 6;            // wave 0..3
  const int l = tid & 63;
  const int lm = l & 15;
  const int q = l >> 4;
  const int colb = w * 64 + lm;      // this lane's base column (cg adds *16)

  __shared__ __align__(16) _Float16 h_lds[2][16 * 256];    // 16KB, swizzled
  __shared__ __align__(16) _Float16 xp_lds[2][16 * 768];   // 48KB, dbuf

  // ---- B fragments resident in registers: bf[role][colgroup][kstep] ----
  // elem j of frag = W[k = kc*32 + q*8 + j][n = ro*256 + colb + cg*16]
  // sched_barrier per (ro,cg): cap in-flight loads at 64 so the allocator
  // never spills the growing bf[] set (R1's 98MB scratch spill, R2d).
  half8v bf[3][4][8];
#pragma unroll
  for (int ro = 0; ro < 3; ++ro)
#pragma unroll
    for (int cg = 0; cg < 4; ++cg) {
#pragma unroll
      for (int kc = 0; kc < 8; ++kc) {
        half8v v;
#pragma unroll
        for (int j = 0; j < 8; ++j) {
          const int k = kc * 32 + q * 8 + j;
          const int c = colb + cg * 16;
          const float wv = (ro < 2) ? Wh_rz[(size_t)k * 512 + ro * 256 + c]
                                    : Wh_n[(size_t)k * 256 + c];
          v[j] = (_Float16)wv;
        }
        bf[ro][cg][kc] = v;
      }
      __builtin_amdgcn_sched_barrier(0);
    }

  float bhn[4];
#pragma unroll
  for (int cg = 0; cg < 4; ++cg) bhn[cg] = bh_n[colb + cg * 16];

  // ---- per-lane xp prefetch sources (u32 byte offsets, +1536/step) ----
  // chunk id c = w*384 + j*64 + l ; row = c/96 ; phys chunk pc = c%96 holds
  // global chunk lc = pc ^ (row&7)  (source pre-swizzle, rule #21).
  unsigned xsrc[6];
#pragma unroll
  for (int j = 0; j < 6; ++j) {
    const int c = w * 384 + j * 64 + l;
    const int row = c / 96;
    const int pc = c - row * 96;
    const int lc = pc ^ (row & 7);
    xsrc[j] = (unsigned)((grp * 16 + row) * T_ + t0) * 1536u + (unsigned)lc * 16u;
  }

  // ---- per-batch-row offsets (4 C-rows per lane: batch = grp*16+q*4+r) ----
  unsigned doff[4];  // byte offset into done
  unsigned yoff[4];  // byte offset into out_ys
  int dcur[4];
#pragma unroll
  for (int r = 0; r < 4; ++r) {
    const int b = grp * 16 + q * 4 + r;
    doff[r] = (unsigned)(b * T_ + t0) * 4u;
    yoff[r] = (unsigned)(b * T_ + t0) * (unsigned)(H_ * 4);
    dcur[r] = *(const int*)((const char*)done + doff[r]);
  }

  // ---- init h tile: chunk 0 starts from h0 (masked by done[b,0]); others 0.
  char* hR = (char*)&h_lds[0][0];
  char* hW = (char*)&h_lds[1][0];
#pragma unroll
  for (int cg = 0; cg < 4; ++cg)
#pragma unroll
    for (int r = 0; r < 4; ++r) {
      const int row = q * 4 + r;
      const int c = colb + cg * 16;
      float v = 0.f;
      if (chunk == 0) {
        const int b = grp * 16 + row;
        v = done[(size_t)b * T_] ? 0.f : h0[(size_t)b * H_ + c];
      }
      *(_Float16*)(hR + swzb(row, c * 2)) = (_Float16)v;
    }

  // ---- prologue prefetch: xp tile for t0 into buf0 ----
  {
    char* xb = (char*)&xp_lds[t0 & 1][0] + w * 6144;
#pragma unroll
    for (int j = 0; j < 6; ++j)
      load16_to_lds((const char*)xp + xsrc[j], xb + j * 1024);
#pragma unroll
    for (int j = 0; j < 6; ++j) xsrc[j] += 1536u;
  }
  __syncthreads();   // drains vmcnt -> h tile + xp(t0) visible

  unsigned act = (chunk == 0) ? 0xFu : 0u;  // batch live for output writes
  unsigned endm = 0u;                        // batch handed to next chunk

  for (int t = t0;;) {
    // flag update with done[b,t] (reset happens BEFORE the step in the ref)
#pragma unroll
    for (int r = 0; r < 4; ++r)
      if (dcur[r]) {
        if (t >= tend) endm |= (1u << r);
        else           act  |= (1u << r);
      }
    if (t >= T_) break;
    if (__all(endm == 0xFu)) break;   // all 16 batches handed off

    const bool hasnext = (t + 1 < T_);

    // done[t+1] loads issued NOW, consumed in the h-write mask ~2K cy later
    int dn[4];
#pragma unroll
    for (int r = 0; r < 4; ++r) {
      const int v = *(const int*)((const char*)done + doff[r] + (hasnext ? 4 : 0));
      dn[r] = hasnext ? v : 0;
    }

    // async prefetch xp tile for t+1 (completion guaranteed by the vmcnt(0)
    // drain at this step's closing __syncthreads)
    if (hasnext) {
      char* xb = (char*)&xp_lds[(t + 1) & 1][0] + w * 6144;
#pragma unroll
      for (int j = 0; j < 6; ++j)
        load16_to_lds((const char*)xp + xsrc[j], xb + j * 1024);
    }
#pragma unroll
    for (int j = 0; j < 6; ++j) xsrc[j] += 1536u;

    const char* xq = (const char*)&xp_lds[t & 1][0];

    // A fragments: h rows (batch=lm), k = kc*32 + q*8 + j
    half8v a[8];
#pragma unroll
    for (int kc = 0; kc < 8; ++kc)
      a[kc] = *(const half8v*)(hR + swzb(lm, kc * 64 + q * 16));

    // two N-halves to cap accumulator liveness at 24 regs
#pragma unroll
    for (int hf = 0; hf < 2; ++hf) {
      f32x4 acc[3][2];
      // acc init: xr -> r-acc, xz -> z-acc, bh_n -> n-acc (xn can't fold:
      // it's outside the r* multiplier). Reads come from LDS (~120cy),
      // prefetched a full step ago.
#pragma unroll
      for (int c2 = 0; c2 < 2; ++c2) {
        const int col = colb + (hf * 2 + c2) * 16;
#pragma unroll
        for (int r = 0; r < 4; ++r) {
          const int row = q * 4 + r;
          acc[0][c2][r] = (float)*(const _Float16*)(xq + xswz(row, col * 2));
          acc[1][c2][r] = (float)*(const _Float16*)(xq + xswz(row, (col + 256) * 2));
          acc[2][c2][r] = bhn[hf * 2 + c2];
        }
      }

#pragma unroll
      for (int kc = 0; kc < 8; ++kc)
#pragma unroll
        for (int ro = 0; ro < 3; ++ro)
#pragma unroll
          for (int c2 = 0; c2 < 2; ++c2)
            acc[ro][c2] = __builtin_amdgcn_mfma_f32_16x16x32_f16(
                a[kc], bf[ro][hf * 2 + c2][kc], acc[ro][c2], 0, 0, 0);

      // epilogue for this half: 8 (batch,col) cells per lane
#pragma unroll
      for (int c2 = 0; c2 < 2; ++c2) {
        const int col = colb + (hf * 2 + c2) * 16;
#pragma unroll
        for (int r = 0; r < 4; ++r) {
          const int row = q * 4 + r;
          const float xn = (float)*(const _Float16*)(xq + xswz(row, (col + 512) * 2));
          const float hm = (float)*(const _Float16*)(hR + swzb(row, col * 2));
          const float rr = 1.f / (1.f + __expf(-acc[0][c2][r]));
          const float zz = 1.f / (1.f + __expf(-acc[1][c2][r]));
          const float npre = xn + rr * acc[2][c2][r];
          const float e = __expf(-2.f * fabsf(npre));   // saturating tanh
          const float tv = (1.f - e) / (1.f + e);
          const float nn = npre < 0.f ? -tv : tv;
          const float hnew = (1.f - zz) * nn + zz * hm;
          // next-step h, masked by done[t+1] (A-reads then need no mask)
          *(_Float16*)(hW + swzb(row, col * 2)) =
              (_Float16)(dn[r] ? 0.f : hnew);
          if (((act >> r) & 1u) && !((endm >> r) & 1u)) {
            *(float*)((char*)out_ys + yoff[r] + (unsigned)col * 4u) = hnew;
            if (t == T_ - 1)
              out_final[(size_t)(grp * 16 + row) * H_ + col] = hnew;
          }
        }
      }
    }

#pragma unroll
    for (int r = 0; r < 4; ++r) {
      doff[r] += 4u;
      yoff[r] += (unsigned)(H_ * 4);
      dcur[r] = dn[r];
    }
    { char* tmp = hR; hR = hW; hW = tmp; }
    ++t;
    __syncthreads();
  }
}

extern "C" void kernel_launch(void* const* d_in, const int* in_sizes, int n_in,
                              void* d_out, int out_size, void* d_ws, size_t ws_size,
                              hipStream_t stream) {
  const float* obs   = (const float*)d_in[0];
  const int*   done  = (const int*)d_in[1];
  const float* h0    = (const float*)d_in[2];
  const float* Wi    = (const float*)d_in[3];
  const float* bi    = (const float*)d_in[4];
  const float* Wh_rz = (const float*)d_in[5];
  const float* Wh_n  = (const float*)d_in[6];
  const float* bh_n  = (const float*)d_in[7];
  float* out = (float*)d_out;                 // [final_h (B*H) | ys (B*T*H)]
  _Float16* xp = (_Float16*)d_ws;             // [131072, 768] f16 (201 MB)

  xproj_gemm<<<dim3(1024, 6), 256, 0, stream>>>(obs, Wi, bi, xp);
  gru_scan_mfma<<<dim3(256), 256, 0, stream>>>(xp, done, h0, Wh_rz, Wh_n, bh_n,
                                               out, out + B_ * H_);
}